// Round 5
// baseline (131.126 us; speedup 1.0000x reference)
//
#include <hip/hip_runtime.h>

// fuzzyConv: B=32, H=W=256, C=32, R=8, O=16, 3x3 VALID -> H'=W'=254
// Premise as implicit GEMM on matrix cores (fp16 features, fp32 accum):
//   exponent_r(p) = sum_{tap,c} [ (s2*mu)*x + (-0.5*s2)*x^2 ] + K_r
// Persistent sliding-band blocks: 6-slot circular LDS row buffer, reg-staged
// prefetch issued one full step ahead, lgkm-only raw barriers (loads stay in
// flight across barriers). Wave-private stride-9 scratch for the epilogue
// transpose (exp writer-side), fp32 epilogue: normalize + 9x16 matvec.

#define CIN 32
#define HH  256
#define WW  256
#define HO  254
#define WO  254
#define BB  32
#define OO  16

#define TW 64
#define BAND 44                     // output rows per block
#define NBAND 6                     // 6*44 >= 254
#define NSTEP 11                    // BAND/4
#define LPIX 66                     // TW+2 staged pixels per row
#define ROWCH (LPIX * 4)            // 264 16-B chunks per row (8 fp16 ch each)
#define SLOTS 6
#define FEAT_CHUNKS (SLOTS * ROWCH) // 1584 chunks = 25344 B
#define SC_STRIDE 9                 // scratch row stride (9 coprime 32 -> conflict-free)
#define SC_WAVE (64 * SC_STRIDE)    // 576 floats per wave
#define PF_CHUNKS (4 * ROWCH)       // 1056 chunks = 4 rows
#define PF_ITERS 5                  // ceil(1056/256)

typedef _Float16 half8 __attribute__((ext_vector_type(8)));   // 8 fp16 (4 VGPR)
typedef float f32x4 __attribute__((ext_vector_type(4)));

static __device__ __forceinline__ unsigned short f2h(float f) {
    _Float16 h = (_Float16)f;
    return *reinterpret_cast<unsigned short*>(&h);
}

static __device__ __forceinline__ half8 pack8(float4 a, float4 b) {
    half8 h;
    h[0] = (_Float16)a.x; h[1] = (_Float16)a.y; h[2] = (_Float16)a.z; h[3] = (_Float16)a.w;
    h[4] = (_Float16)b.x; h[5] = (_Float16)b.y; h[6] = (_Float16)b.z; h[7] = (_Float16)b.w;
    return h;
}

// Raw barrier: lgkmcnt(0) only — does NOT drain vmcnt, so prefetch global
// loads stay in flight across it (the whole point of the pipeline).
static __device__ __forceinline__ void block_sync_lds() {
    asm volatile("s_waitcnt lgkmcnt(0)" ::: "memory");
    __builtin_amdgcn_s_barrier();
    asm volatile("" ::: "memory");
}

// ---------------- prep: B-fragments (fp16) + K constants ----------------
// wb: 18 frags = tap(9) x ftype(2); ftype0 pairs with x (w = s2*mu),
// ftype1 pairs with x^2 (w = -0.5*s2). lane l -> n=l&15 (rule, 0-pad n>=8),
// k-element e -> channel c = (l>>4)*8+e.
__global__ __launch_bounds__(256) void prep_kernel(const float* __restrict__ sigma,
                                                   const float* __restrict__ mu,
                                                   unsigned short* __restrict__ wb,
                                                   float* __restrict__ Kc) {
    const int tid = threadIdx.x;
    for (int item = tid; item < 18 * 64; item += 256) {
        const int frag = item >> 6;          // 0..17
        const int lane = item & 63;
        const int tap = frag >> 1, ftype = frag & 1;
        const int n = lane & 15, g = lane >> 4;
#pragma unroll
        for (int e = 0; e < 8; ++e) {
            float wgt = 0.f;
            if (n < 8) {
                const int c = g * 8 + e;
                const float sg = sigma[(tap * CIN + c) * 8 + n];   // (3,3,C,R)
                const float s2 = sg * sg;
                wgt = ftype ? -0.5f * s2 : s2 * mu[n * CIN + c];
            }
            wb[item * 8 + e] = f2h(wgt);
        }
    }
    if (tid < 8) {
        const int r = tid;
        float k = 0.f;
        for (int item = 0; item < 9 * CIN; ++item) {
            const int c = item & 31;
            const float sg = sigma[item * 8 + r];
            const float m = mu[r * CIN + c];
            k = fmaf(sg * sg, m * m, k);
        }
        Kc[r] = -0.5f * k;
    }
}

// ---------------- main kernel ----------------
__global__ __launch_bounds__(256, 3) void fuzzy_main(const float* __restrict__ x,
                                                     const unsigned short* __restrict__ wb,
                                                     const float* __restrict__ Kc,
                                                     const float* __restrict__ residual,
                                                     const float* __restrict__ cb,
                                                     float* __restrict__ out) {
    __shared__ __align__(16) unsigned char ldsRaw[FEAT_CHUNKS * 16 + 4 * SC_WAVE * 4]; // 25344+9216
    half8* ldsH = reinterpret_cast<half8*>(ldsRaw);
    float* scratch = reinterpret_cast<float*>(ldsRaw + FEAT_CHUNKS * 16);

    const int tid  = threadIdx.x;
    const int jt   = blockIdx.x;               // 0..3
    const int band = blockIdx.y;               // 0..5
    const int b    = blockIdx.z;               // 0..31
    const int i0 = min(BAND * band, HO - BAND);   // 0,44,...,176,210 (overlap dup at edge)
    const int j0 = min(TW * jt, WO - TW);

    // row r, chunk c (32B): xstrip + r*2048 + 2*c (float4 units)
    const float4* xstrip = reinterpret_cast<const float4*>(x)
                         + ((size_t)b * HH * WW + (size_t)j0) * (CIN / 4);

    // ---- prologue: stage rows i0..i0+5 ----
    {
        float4 va[7], vb[7];
#pragma unroll
        for (int k = 0; k < 7; ++k) {
            const int f = tid + (k << 8);
            const int fc = (f < FEAT_CHUNKS) ? f : (FEAT_CHUNKS - 1);
            const int rl = fc / ROWCH;
            const int rem = fc - rl * ROWCH;
            const float4* src = xstrip + (size_t)(i0 + rl) * 2048 + 2 * rem;
            va[k] = src[0]; vb[k] = src[1];
        }
#pragma unroll
        for (int k = 0; k < 7; ++k) {
            const int f = tid + (k << 8);
            if (f < FEAT_CHUNKS) {
                const int rl = f / ROWCH;
                const int rem = f - rl * ROWCH;
                const int s = (i0 + rl) % 6;
                const int px = rem >> 2, gg = rem & 3;
                ldsH[s * ROWCH + (px << 2) + (gg ^ (px & 3))] = pack8(va[k], vb[k]);
            }
        }
    }

    const int lane = tid & 63;
    const int wv_  = tid >> 6;                 // wave id = row offset within step
    const int m = lane & 15, g = lane >> 4;

    // B-fragments resident (18 x 4 VGPR)
    half8 Bf[18];
    const half8* wbv = reinterpret_cast<const half8*>(wb);
#pragma unroll
    for (int q = 0; q < 18; ++q) Bf[q] = wbv[q * 64 + lane];

    const float kcm = Kc[m & 7];
    const float res = residual[0];

    int bc[3];
#pragma unroll
    for (int kj = 0; kj < 3; ++kj) { const int p = m + kj; bc[kj] = (p << 2) + (g ^ (p & 3)); }

    __syncthreads();   // prologue barrier (one-time vmcnt drain is fine)

    // ---- initial prefetch: rows i0+6..i0+9 into regs ----
    float4 pa[PF_ITERS], pb[PF_ITERS];
#pragma unroll
    for (int k = 0; k < PF_ITERS; ++k) {
        const int f = tid + (k << 8);
        if (f < PF_CHUNKS) {
            const int rl = f / ROWCH;
            const int rem = f - rl * ROWCH;
            const float4* src = xstrip + (size_t)(i0 + 6 + rl) * 2048 + 2 * rem;
            pa[k] = src[0]; pb[k] = src[1];
        }
    }

    int s0 = i0 % 6;                            // slot of row r0 = i0+4t
#pragma unroll 1
    for (int t = 0; t < NSTEP; ++t) {
        const int r0 = i0 + 4 * t;

        const half8* rp[3];
#pragma unroll
        for (int ki = 0; ki < 3; ++ki) {
            int s = s0 + wv_ + ki;              // <= 5+3+2=10
            if (s >= 6) s -= 6;
            rp[ki] = ldsH + s * ROWCH;
        }

        f32x4 acc[4];
#pragma unroll
        for (int mt = 0; mt < 4; ++mt) acc[mt] = (f32x4){0.f, 0.f, 0.f, 0.f};

#pragma unroll
        for (int ki = 0; ki < 3; ++ki) {
#pragma unroll
            for (int kj = 0; kj < 3; ++kj) {
                const int tap = ki * 3 + kj;
                half8 ax[4];
#pragma unroll
                for (int mt = 0; mt < 4; ++mt) ax[mt] = rp[ki][mt * 64 + bc[kj]];
#pragma unroll
                for (int mt = 0; mt < 4; ++mt)
                    acc[mt] = __builtin_amdgcn_mfma_f32_16x16x32_f16(ax[mt], Bf[2 * tap], acc[mt], 0, 0, 0);
#pragma unroll
                for (int mt = 0; mt < 4; ++mt) {
                    const half8 ax2 = ax[mt] * ax[mt];        // v_pk_mul_f16
                    acc[mt] = __builtin_amdgcn_mfma_f32_16x16x32_f16(ax2, Bf[2 * tap + 1], acc[mt], 0, 0, 0);
                }
            }
        }

        // phi = exp(acc + K) -> wave-private scratch (stride 9, conflict-free)
        float* scW = scratch + wv_ * SC_WAVE;
        if (m < 8) {
#pragma unroll
            for (int mt = 0; mt < 4; ++mt)
#pragma unroll
                for (int e = 0; e < 4; ++e)
                    scW[(mt * 16 + g * 4 + e) * SC_STRIDE + m] = __expf(acc[mt][e] + kcm);
        }

        block_sync_lds();   // barrier1: all feature reads + scratch writes done

        // restage rows r0+6..r0+9 from regs (loaded one full step ago)
        if (t < NSTEP - 1) {
#pragma unroll
            for (int k = 0; k < PF_ITERS; ++k) {
                const int f = tid + (k << 8);
                if (f < PF_CHUNKS) {
                    const int rl = f / ROWCH;
                    const int rem = f - rl * ROWCH;
                    int s = s0 + rl; if (s >= 6) s -= 6;   // (r0+6+rl)%6
                    const int px = rem >> 2, gg = rem & 3;
                    ldsH[s * ROWCH + (px << 2) + (gg ^ (px & 3))] = pack8(pa[k], pb[k]);
                }
            }
        }
        // issue loads for rows r0+10..r0+13 (consumed next iteration)
        if (t < NSTEP - 2) {
#pragma unroll
            for (int k = 0; k < PF_ITERS; ++k) {
                const int f = tid + (k << 8);
                if (f < PF_CHUNKS) {
                    const int rl = f / ROWCH;
                    const int rem = f - rl * ROWCH;
                    const float4* src = xstrip + (size_t)(r0 + 10 + rl) * 2048 + 2 * rem;
                    pa[k] = src[0]; pb[k] = src[1];
                }
            }
        }

        // epilogue: lane = pixel; normalize + 9x16 matvec (cb uniform -> s_load)
        {
            const float* scR = scratch + wv_ * SC_WAVE + lane * SC_STRIDE;
            float ph[8];
            float ssum = res + 1e-9f;
#pragma unroll
            for (int r = 0; r < 8; ++r) { ph[r] = scR[r]; ssum += ph[r]; }
            const float inv = 1.0f / ssum;
            const int ro = r0 + wv_;
            float* op = out + (((size_t)b * HO + ro) * WO + (size_t)(j0 + lane)) * OO;
#pragma unroll
            for (int o4 = 0; o4 < 4; ++o4) {
                float4 v;
#pragma unroll
                for (int q = 0; q < 4; ++q) {
                    const int o = o4 * 4 + q;
                    float a = res * cb[8 * OO + o];
#pragma unroll
                    for (int r = 0; r < 8; ++r) a = fmaf(ph[r], cb[r * OO + o], a);
                    ((float*)&v)[q] = a * inv;
                }
                *reinterpret_cast<float4*>(op + o4 * 4) = v;
            }
        }

        block_sync_lds();   // barrier2: restaged rows visible for next step

        s0 += 4; if (s0 >= 6) s0 -= 6;
    }
}

extern "C" void kernel_launch(void* const* d_in, const int* in_sizes, int n_in,
                              void* d_out, int out_size, void* d_ws, size_t ws_size,
                              hipStream_t stream) {
    const float* x     = (const float*)d_in[0];
    const float* sigma = (const float*)d_in[1];   // (3,3,32,8)
    const float* mu    = (const float*)d_in[2];   // (8,32)
    const float* resid = (const float*)d_in[3];   // (1,)
    const float* cb    = (const float*)d_in[4];   // (9,16)
    float* outp = (float*)d_out;

    float* Kc = (float*)d_ws;                          // 8 floats
    unsigned short* wb = (unsigned short*)(Kc + 8);    // 18*64*8 fp16 = 18432 B

    hipLaunchKernelGGL(prep_kernel, dim3(1), dim3(256), 0, stream, sigma, mu, wb, Kc);
    hipLaunchKernelGGL(fuzzy_main, dim3(4, NBAND, BB), dim3(256), 0, stream,
                       x, wb, Kc, resid, cb, outp);
}

// Round 7
// 100.550 us; speedup vs baseline: 1.3041x; 1.3041x over previous
//
#include <hip/hip_runtime.h>

// fuzzyConv: B=32, H=W=256, C=32, R=8, O=16, 3x3 VALID -> H'=W'=254
// Premise as implicit GEMM on matrix cores (fp16 features, fp32 accum),
// OPERAND-SWAPPED: D1[rule,pixel] = W·X so the epilogue needs no transpose.
//   exponent_r(p) = sum_{tap,c} [ (s2*mu)*x + (-0.5*s2)*x^2 ] + K_r
// Epilogue fully in-register: exp, shfl-reduced denominator, second MFMA
// out[o,p] = cb^T · phi_aug (residual rule injected as k-row 8), coalesced
// nontemporal float4 stores. ONE barrier per block.

#define CIN 32
#define HH  256
#define WW  256
#define HO  254
#define WO  254
#define BB  32
#define OO  16

#define TW 64
#define TH 4
#define LROWS 6                     // TH+2 staged input rows
#define LPIX 66                     // TW+2 staged pixels per row
#define ROWCH (LPIX * 4)            // 264 16-B chunks per row (8 fp16 ch each)
#define LDS_CHUNKS (LROWS * ROWCH)  // 1584 chunks = 25344 B
#define STAGE_ITERS 7               // ceil(1584/256)

typedef _Float16 half8 __attribute__((ext_vector_type(8)));   // 8 fp16 (4 VGPR)
typedef float f32x4 __attribute__((ext_vector_type(4)));

static __device__ __forceinline__ unsigned short f2h(float f) {
    _Float16 h = (_Float16)f;
    return *reinterpret_cast<unsigned short*>(&h);
}

// ---------------- prep: W-fragments (fp16) + K constants ----------------
// wb: 18 frags = tap(9) x ftype(2); ftype0 pairs with x (w = s2*mu),
// ftype1 pairs with x^2 (w = -0.5*s2). A-operand layout: lane l -> row
// m=l&15 = rule (0-pad >=8), k-element e -> channel c = (l>>4)*8+e.
__global__ __launch_bounds__(256) void prep_kernel(const float* __restrict__ sigma,
                                                   const float* __restrict__ mu,
                                                   unsigned short* __restrict__ wb,
                                                   float* __restrict__ Kc) {
    const int tid = threadIdx.x;
    for (int item = tid; item < 18 * 64; item += 256) {
        const int frag = item >> 6;          // 0..17
        const int lane = item & 63;
        const int tap = frag >> 1, ftype = frag & 1;
        const int n = lane & 15, g = lane >> 4;
#pragma unroll
        for (int e = 0; e < 8; ++e) {
            float wgt = 0.f;
            if (n < 8) {
                const int c = g * 8 + e;
                const float sg = sigma[(tap * CIN + c) * 8 + n];   // (3,3,C,R)
                const float s2 = sg * sg;
                wgt = ftype ? -0.5f * s2 : s2 * mu[n * CIN + c];
            }
            wb[item * 8 + e] = f2h(wgt);
        }
    }
    if (tid < 8) {
        const int r = tid;
        float k = 0.f;
        for (int item = 0; item < 9 * CIN; ++item) {
            const int c = item & 31;
            const float sg = sigma[item * 8 + r];
            const float m = mu[r * CIN + c];
            k = fmaf(sg * sg, m * m, k);
        }
        Kc[r] = -0.5f * k;
    }
}

// ---------------- main kernel ----------------
// Block 256 = 4 waves; wave w owns output row (i0+w), 64 px = 4 N-tiles of 16.
// LDS: 6 rows x 66 px x 32ch fp16 x, chunk-swizzled (g ^ (px&3)).
__global__ __launch_bounds__(256, 4) void fuzzy_main(const float* __restrict__ x,
                                                     const unsigned short* __restrict__ wb,
                                                     const float* __restrict__ Kc,
                                                     const float* __restrict__ residual,
                                                     const float* __restrict__ cb,
                                                     float* __restrict__ out) {
    __shared__ __align__(16) unsigned char ldsRaw[LDS_CHUNKS * 16];   // 25344 B
    half8* ldsH = reinterpret_cast<half8*>(ldsRaw);

    const int tid = threadIdx.x;
    const int jt = blockIdx.x;              // 0..3
    const int it = blockIdx.y;              // 0..63
    const int b  = blockIdx.z;              // 0..31
    const int i0 = min(TH * it, HO - TH);   // clamped (edge tiles duplicate compute)
    const int j0 = min(TW * jt, WO - TW);

    // ---- stage: issue ALL global loads first, then convert + swizzled LDS write ----
    float4 va[STAGE_ITERS], vb[STAGE_ITERS];
#pragma unroll
    for (int t = 0; t < STAGE_ITERS; ++t) {
        const int f = tid + t * 256;
        const int fc = min(f, LDS_CHUNKS - 1);
        const int row = fc / ROWCH;
        const int rem = fc - row * ROWCH;
        const float4* src = reinterpret_cast<const float4*>(
            x + (((size_t)b * HH + (size_t)(i0 + row)) * WW + (size_t)j0) * CIN);
        va[t] = src[2 * rem];
        vb[t] = src[2 * rem + 1];
    }
#pragma unroll
    for (int t = 0; t < STAGE_ITERS; ++t) {
        const int f = tid + t * 256;
        if (f < LDS_CHUNKS) {
            const int row = f / ROWCH;
            const int rem = f - row * ROWCH;
            const int px = rem >> 2, gg = rem & 3;
            half8 h;
            h[0] = (_Float16)va[t].x; h[1] = (_Float16)va[t].y;
            h[2] = (_Float16)va[t].z; h[3] = (_Float16)va[t].w;
            h[4] = (_Float16)vb[t].x; h[5] = (_Float16)vb[t].y;
            h[6] = (_Float16)vb[t].z; h[7] = (_Float16)vb[t].w;
            ldsH[row * ROWCH + (px << 2) + (gg ^ (px & 3))] = h;
        }
    }

    const int lane = tid & 63;
    const int m = lane & 15, g = lane >> 4;

    // ---- W-fragments resident (18 x 4 VGPR) ----
    const half8* wbv = reinterpret_cast<const half8*>(wb);
    half8 Bf[18];
#pragma unroll
    for (int q = 0; q < 18; ++q) Bf[q] = wbv[q * 64 + lane];

    // ---- epilogue constants (pre-barrier, overlaps staging latency) ----
    const float res = residual[0];
    // kc4: rules g*4+e for this lane's D1 rows (g<2 real)
    const float4 kc4 = reinterpret_cast<const float4*>(Kc)[g & 1];
    // A2 = cb^T fragment: row o = m, k-row r = g*8+e (r<9 real)
    half8 a2;
#pragma unroll
    for (int e = 0; e < 8; ++e) {
        const int r = g * 8 + e;
        const float w = cb[min(r, 8) * OO + m];
        a2[e] = (_Float16)((r <= 8) ? w : 0.f);
    }
    unsigned resw;
    { unsigned short rb = f2h(res); resw = (unsigned)rb; }  // fp16 res in low half

    __syncthreads();

    const int wv_ = tid >> 6;               // wave id = tile row

    // per-lane chunk offset per kj (nt adds nt*64): pixel p = m+kj,
    // chunk = p*4 + (g ^ (p&3))
    int bc[3];
#pragma unroll
    for (int kj = 0; kj < 3; ++kj) {
        const int p = m + kj;
        bc[kj] = (p << 2) + (g ^ (p & 3));
    }

    f32x4 acc[4];
#pragma unroll
    for (int nt = 0; nt < 4; ++nt) acc[nt] = (f32x4){0.f, 0.f, 0.f, 0.f};

    const half8* baseS = ldsH + wv_ * ROWCH;
#pragma unroll
    for (int ki = 0; ki < 3; ++ki) {
#pragma unroll
        for (int kj = 0; kj < 3; ++kj) {
            const int tap = ki * 3 + kj;
            half8 ax[4];
#pragma unroll
            for (int nt = 0; nt < 4; ++nt)
                ax[nt] = baseS[ki * ROWCH + nt * 64 + bc[kj]];
#pragma unroll
            for (int nt = 0; nt < 4; ++nt)   // D1 = W·X (weights are A-operand)
                acc[nt] = __builtin_amdgcn_mfma_f32_16x16x32_f16(Bf[2 * tap], ax[nt], acc[nt], 0, 0, 0);
#pragma unroll
            for (int nt = 0; nt < 4; ++nt) {
                const half8 ax2 = ax[nt] * ax[nt];           // v_pk_mul_f16
                acc[nt] = __builtin_amdgcn_mfma_f32_16x16x32_f16(Bf[2 * tap + 1], ax2, acc[nt], 0, 0, 0);
            }
        }
    }

    // ---- in-register epilogue per 16-pixel tile ----
    const size_t orow = ((size_t)b * HO + (size_t)(i0 + wv_)) * WO + (size_t)j0;
#pragma unroll
    for (int nt = 0; nt < 4; ++nt) {
        // phi for this lane's 4 rules (g<2 real; pads -> 0)
        float phv[4];
#pragma unroll
        for (int e = 0; e < 4; ++e) {
            const float t = __expf(acc[nt][e] + ((const float*)&kc4)[e]);
            phv[e] = (g < 2) ? t : 0.f;
        }
        // denominator: sum over 8 rules (pairs of g) + residual
        const float S = (phv[0] + phv[1]) + (phv[2] + phv[3]);
        const float T = S + __shfl_xor(S, 16);
        const float denom = T + __shfl_xor(T, 32) + res + 1e-9f;
        const float inv = __builtin_amdgcn_rcpf(denom);

        // pack phi -> fp16 pairs; gather partner rules (g0 needs g1's r4..7)
        const unsigned w01 = (unsigned)f2h(phv[0]) | ((unsigned)f2h(phv[1]) << 16);
        const unsigned w23 = (unsigned)f2h(phv[2]) | ((unsigned)f2h(phv[3]) << 16);
        const unsigned p01 = __shfl_xor(w01, 16);
        const unsigned p23 = __shfl_xor(w23, 16);
        uint4 bw;
        bw.x = (g == 0) ? w01 : ((g == 1) ? resw : 0u);   // g1 k-row 8 = residual
        bw.y = (g == 0) ? w23 : 0u;
        bw.z = (g == 0) ? p01 : 0u;
        bw.w = (g == 0) ? p23 : 0u;
        const half8 b2 = __builtin_bit_cast(half8, bw);

        f32x4 acc2 = (f32x4){0.f, 0.f, 0.f, 0.f};
        acc2 = __builtin_amdgcn_mfma_f32_16x16x32_f16(a2, b2, acc2, 0, 0, 0);

        f32x4 v;
        v[0] = acc2[0] * inv; v[1] = acc2[1] * inv;
        v[2] = acc2[2] * inv; v[3] = acc2[3] * inv;
        float* op = out + (orow + (size_t)(nt * 16 + m)) * OO + g * 4;
        __builtin_nontemporal_store(v, reinterpret_cast<f32x4*>(op));
    }
}

extern "C" void kernel_launch(void* const* d_in, const int* in_sizes, int n_in,
                              void* d_out, int out_size, void* d_ws, size_t ws_size,
                              hipStream_t stream) {
    const float* x     = (const float*)d_in[0];
    const float* sigma = (const float*)d_in[1];   // (3,3,32,8)
    const float* mu    = (const float*)d_in[2];   // (8,32)
    const float* resid = (const float*)d_in[3];   // (1,)
    const float* cb    = (const float*)d_in[4];   // (9,16)
    float* outp = (float*)d_out;

    float* Kc = (float*)d_ws;                          // 8 floats
    unsigned short* wb = (unsigned short*)(Kc + 8);    // 18*64*8 fp16 = 18432 B

    hipLaunchKernelGGL(prep_kernel, dim3(1), dim3(256), 0, stream, sigma, mu, wb, Kc);
    hipLaunchKernelGGL(fuzzy_main, dim3(4, 64, BB), dim3(256), 0, stream,
                       x, wb, Kc, resid, cb, outp);
}

// Round 8
// 86.338 us; speedup vs baseline: 1.5188x; 1.1646x over previous
//
#include <hip/hip_runtime.h>

// fuzzyConv: B=32, H=W=256, C=32, R=8, O=16, 3x3 VALID -> H'=W'=254
// Premise as implicit GEMM on matrix cores (fp16 features, fp32 accum),
// OPERAND-SWAPPED: D1[rule,pixel] = W·X so the epilogue needs no transpose.
//   exponent_r(p) = sum_{tap,c} [ (s2*mu)*x + (-0.5*s2)*x^2 ] + K_r
// TH=8 tile (10 staged rows / 8 output rows -> 1.25x read demand), chunked
// XCD swizzle so vertical halo neighbors share an XCD L2. Epilogue fully
// in-register: exp, shfl denominator, second MFMA out = cb^T·phi_aug,
// nontemporal float4 stores. ONE barrier per block.

#define CIN 32
#define HH  256
#define WW  256
#define HO  254
#define WO  254
#define BB  32
#define OO  16

#define TW 64
#define TH 8
#define LROWS 10                    // TH+2 staged input rows
#define LPIX 66                     // TW+2 staged pixels per row
#define ROWCH (LPIX * 4)            // 264 16-B chunks per row (8 fp16 ch each)
#define LDS_CHUNKS (LROWS * ROWCH)  // 2640 chunks = 42240 B
#define STAGE_ITERS 11              // ceil(2640/256)
#define NTILE (4 * 32 * BB)         // 4096 blocks

typedef _Float16 half8 __attribute__((ext_vector_type(8)));   // 8 fp16 (4 VGPR)
typedef float f32x4 __attribute__((ext_vector_type(4)));

static __device__ __forceinline__ unsigned short f2h(float f) {
    _Float16 h = (_Float16)f;
    return *reinterpret_cast<unsigned short*>(&h);
}

// ---------------- prep: W-fragments (fp16) + K constants ----------------
// wb: 18 frags = tap(9) x ftype(2); ftype0 pairs with x (w = s2*mu),
// ftype1 pairs with x^2 (w = -0.5*s2). A-operand layout: lane l -> row
// m=l&15 = rule (0-pad >=8), k-element e -> channel c = (l>>4)*8+e.
__global__ __launch_bounds__(256) void prep_kernel(const float* __restrict__ sigma,
                                                   const float* __restrict__ mu,
                                                   unsigned short* __restrict__ wb,
                                                   float* __restrict__ Kc) {
    const int tid = threadIdx.x;
    for (int item = tid; item < 18 * 64; item += 256) {
        const int frag = item >> 6;          // 0..17
        const int lane = item & 63;
        const int tap = frag >> 1, ftype = frag & 1;
        const int n = lane & 15, g = lane >> 4;
#pragma unroll
        for (int e = 0; e < 8; ++e) {
            float wgt = 0.f;
            if (n < 8) {
                const int c = g * 8 + e;
                const float sg = sigma[(tap * CIN + c) * 8 + n];   // (3,3,C,R)
                const float s2 = sg * sg;
                wgt = ftype ? -0.5f * s2 : s2 * mu[n * CIN + c];
            }
            wb[item * 8 + e] = f2h(wgt);
        }
    }
    if (tid < 8) {
        const int r = tid;
        float k = 0.f;
        for (int item = 0; item < 9 * CIN; ++item) {
            const int c = item & 31;
            const float sg = sigma[item * 8 + r];
            const float m = mu[r * CIN + c];
            k = fmaf(sg * sg, m * m, k);
        }
        Kc[r] = -0.5f * k;
    }
}

// ---------------- main kernel ----------------
// Block 256 = 4 waves; wave w owns output rows (i0+w) and (i0+w+4);
// 64 px = 4 N-tiles of 16. LDS: 10 rows x 66 px x 32ch fp16, swizzled.
__global__ __launch_bounds__(256, 3) void fuzzy_main(const float* __restrict__ x,
                                                     const unsigned short* __restrict__ wb,
                                                     const float* __restrict__ Kc,
                                                     const float* __restrict__ residual,
                                                     const float* __restrict__ cb,
                                                     float* __restrict__ out) {
    __shared__ __align__(16) unsigned char ldsRaw[LDS_CHUNKS * 16];   // 42240 B
    half8* ldsH = reinterpret_cast<half8*>(ldsRaw);

    const int tid = threadIdx.x;
    // chunked XCD swizzle: XCD k gets a contiguous band of tiles ordered
    // (b, it, jt)-major -> vertical halo neighbors on the same XCD L2.
    const int lin  = blockIdx.x;
    const int tile = ((lin & 7) << 9) | (lin >> 3);   // 4096 = 8 * 512, bijective
    const int jt = tile & 3;
    const int it = (tile >> 2) & 31;
    const int b  = tile >> 7;
    const int i0 = min(TH * it, HO - TH);   // clamped (edge tiles duplicate compute)
    const int j0 = min(TW * jt, WO - TW);

    // ---- stage: issue ALL global loads first, then convert + swizzled LDS write ----
    float4 va[STAGE_ITERS], vb[STAGE_ITERS];
#pragma unroll
    for (int t = 0; t < STAGE_ITERS; ++t) {
        const int f = tid + t * 256;
        const int fc = min(f, LDS_CHUNKS - 1);
        const int row = fc / ROWCH;
        const int rem = fc - row * ROWCH;
        const float4* src = reinterpret_cast<const float4*>(
            x + (((size_t)b * HH + (size_t)(i0 + row)) * WW + (size_t)j0) * CIN);
        va[t] = src[2 * rem];
        vb[t] = src[2 * rem + 1];
    }
#pragma unroll
    for (int t = 0; t < STAGE_ITERS; ++t) {
        const int f = tid + t * 256;
        if (f < LDS_CHUNKS) {
            const int row = f / ROWCH;
            const int rem = f - row * ROWCH;
            const int px = rem >> 2, gg = rem & 3;
            half8 h;
            h[0] = (_Float16)va[t].x; h[1] = (_Float16)va[t].y;
            h[2] = (_Float16)va[t].z; h[3] = (_Float16)va[t].w;
            h[4] = (_Float16)vb[t].x; h[5] = (_Float16)vb[t].y;
            h[6] = (_Float16)vb[t].z; h[7] = (_Float16)vb[t].w;
            ldsH[row * ROWCH + (px << 2) + (gg ^ (px & 3))] = h;
        }
    }

    const int lane = tid & 63;
    const int m = lane & 15, g = lane >> 4;

    // ---- W-fragments resident (18 x 4 VGPR) ----
    const half8* wbv = reinterpret_cast<const half8*>(wb);
    half8 Bf[18];
#pragma unroll
    for (int q = 0; q < 18; ++q) Bf[q] = wbv[q * 64 + lane];

    // ---- epilogue constants (pre-barrier, overlaps staging latency) ----
    const float res = residual[0];
    const float4 kc4 = reinterpret_cast<const float4*>(Kc)[g & 1];
    half8 a2;                                // cb^T frag: row o=m, k-row r=g*8+e
#pragma unroll
    for (int e = 0; e < 8; ++e) {
        const int r = g * 8 + e;
        const float w = cb[min(r, 8) * OO + m];
        a2[e] = (_Float16)((r <= 8) ? w : 0.f);
    }
    unsigned resw;
    { unsigned short rb = f2h(res); resw = (unsigned)rb; }  // fp16 res, low half

    __syncthreads();

    const int wv_ = tid >> 6;

    // per-lane chunk offset per kj (nt adds nt*64): pixel p = m+kj
    int bc[3];
#pragma unroll
    for (int kj = 0; kj < 3; ++kj) {
        const int p = m + kj;
        bc[kj] = (p << 2) + (g ^ (p & 3));
    }

#pragma unroll
    for (int half = 0; half < 2; ++half) {
        const int row0 = wv_ + 4 * half;     // staged-row base for this output row

        f32x4 acc[4];
#pragma unroll
        for (int nt = 0; nt < 4; ++nt) acc[nt] = (f32x4){0.f, 0.f, 0.f, 0.f};

        const half8* baseS = ldsH + row0 * ROWCH;
#pragma unroll
        for (int ki = 0; ki < 3; ++ki) {
#pragma unroll
            for (int kj = 0; kj < 3; ++kj) {
                const int tap = ki * 3 + kj;
                half8 ax[4];
#pragma unroll
                for (int nt = 0; nt < 4; ++nt)
                    ax[nt] = baseS[ki * ROWCH + nt * 64 + bc[kj]];
#pragma unroll
                for (int nt = 0; nt < 4; ++nt)   // D1 = W·X
                    acc[nt] = __builtin_amdgcn_mfma_f32_16x16x32_f16(Bf[2 * tap], ax[nt], acc[nt], 0, 0, 0);
#pragma unroll
                for (int nt = 0; nt < 4; ++nt) {
                    const half8 ax2 = ax[nt] * ax[nt];       // v_pk_mul_f16
                    acc[nt] = __builtin_amdgcn_mfma_f32_16x16x32_f16(Bf[2 * tap + 1], ax2, acc[nt], 0, 0, 0);
                }
            }
        }

        // ---- in-register epilogue per 16-pixel tile ----
        const size_t orow = ((size_t)b * HO + (size_t)(i0 + wv_ + 4 * half)) * WO + (size_t)j0;
#pragma unroll
        for (int nt = 0; nt < 4; ++nt) {
            float phv[4];
#pragma unroll
            for (int e = 0; e < 4; ++e) {
                const float t = __expf(acc[nt][e] + ((const float*)&kc4)[e]);
                phv[e] = (g < 2) ? t : 0.f;
            }
            const float S = (phv[0] + phv[1]) + (phv[2] + phv[3]);
            const float T = S + __shfl_xor(S, 16);
            const float denom = T + __shfl_xor(T, 32) + res + 1e-9f;
            const float inv = __builtin_amdgcn_rcpf(denom);

            const unsigned w01 = (unsigned)f2h(phv[0]) | ((unsigned)f2h(phv[1]) << 16);
            const unsigned w23 = (unsigned)f2h(phv[2]) | ((unsigned)f2h(phv[3]) << 16);
            const unsigned p01 = __shfl_xor(w01, 16);
            const unsigned p23 = __shfl_xor(w23, 16);
            uint4 bw;
            bw.x = (g == 0) ? w01 : ((g == 1) ? resw : 0u);   // g1 k-row 8 = residual
            bw.y = (g == 0) ? w23 : 0u;
            bw.z = (g == 0) ? p01 : 0u;
            bw.w = (g == 0) ? p23 : 0u;
            const half8 b2 = __builtin_bit_cast(half8, bw);

            f32x4 acc2 = (f32x4){0.f, 0.f, 0.f, 0.f};
            acc2 = __builtin_amdgcn_mfma_f32_16x16x32_f16(a2, b2, acc2, 0, 0, 0);

            f32x4 v;
            v[0] = acc2[0] * inv; v[1] = acc2[1] * inv;
            v[2] = acc2[2] * inv; v[3] = acc2[3] * inv;
            float* op = out + (orow + (size_t)(nt * 16 + m)) * OO + g * 4;
            __builtin_nontemporal_store(v, reinterpret_cast<f32x4*>(op));
        }
    }
}

extern "C" void kernel_launch(void* const* d_in, const int* in_sizes, int n_in,
                              void* d_out, int out_size, void* d_ws, size_t ws_size,
                              hipStream_t stream) {
    const float* x     = (const float*)d_in[0];
    const float* sigma = (const float*)d_in[1];   // (3,3,32,8)
    const float* mu    = (const float*)d_in[2];   // (8,32)
    const float* resid = (const float*)d_in[3];   // (1,)
    const float* cb    = (const float*)d_in[4];   // (9,16)
    float* outp = (float*)d_out;

    float* Kc = (float*)d_ws;                          // 8 floats
    unsigned short* wb = (unsigned short*)(Kc + 8);    // 18*64*8 fp16 = 18432 B

    hipLaunchKernelGGL(prep_kernel, dim3(1), dim3(256), 0, stream, sigma, mu, wb, Kc);
    hipLaunchKernelGGL(fuzzy_main, dim3(NTILE), dim3(256), 0, stream,
                       x, wb, Kc, resid, cb, outp);
}